// Round 1
// 182.434 us; speedup vs baseline: 1.1414x; 1.1414x over previous
//
#include <hip/hip_runtime.h>
#include <hip/hip_bf16.h>
#include <math.h>

// Problem constants
#define HID   64
#define VOCABN 64
#define INNER 24
#define SEQN  32
#define CAPN  8
#define NPOS  17
#define BATCHN 8192

typedef float f32x4 __attribute__((ext_vector_type(4)));

// Per-step Adam prefactor (double-precision offline):
//   cmsbr[t] = LR * sqrt(1 - B2^(t+1)) / (1 - B1^(t+1)),  t = 0..7
static __device__ const float CMSBR[8] = {
  0.01581139f, 0.01176584f, 0.01010053f, 0.00918844f,
  0.00862495f, 0.00825540f, 0.00800653f, 0.00783856f
};

// ---------- 32-lane all-reduce over u = lane&31 ----------
// Bit-exact continuation of the r4-r11 allred64 butterfly: the first (xor1)
// stage is folded into an in-register pair add by the caller; these 5 stages
// reproduce old xor2/xor4/xor8/xor16/xor32 on the pair-sums (u^1,u^2,u^4,
// u^8,u^16), same operand order (x += fetched).
__device__ __forceinline__ float allred32(float x) {
  int y;
  y = __builtin_amdgcn_update_dpp(__float_as_int(x), __float_as_int(x),
                                  0xB1, 0xF, 0xF, false);   // quad_perm u^1
  x += __int_as_float(y);
  y = __builtin_amdgcn_update_dpp(__float_as_int(x), __float_as_int(x),
                                  0x4E, 0xF, 0xF, false);   // quad_perm u^2
  x += __int_as_float(y);
  x += __int_as_float(__builtin_amdgcn_ds_swizzle(__float_as_int(x), 0x101F)); // u^4
  x += __int_as_float(__builtin_amdgcn_ds_swizzle(__float_as_int(x), 0x201F)); // u^8
  x += __int_as_float(__builtin_amdgcn_ds_swizzle(__float_as_int(x), 0x401F)); // u^16
  return x;
}

// ---------- Kernel 1: per-token encoder table (verbatim, passing) ----------
__global__ __launch_bounds__(128) void build_table(
    const float* __restrict__ embed,    // [64][64]
    const float* __restrict__ ff_w1,    // [64][128]
    const float* __restrict__ ff_b1,    // [128]
    const float* __restrict__ ff_w2,    // [128][64]
    const float* __restrict__ ff_b2,    // [64]
    const float* __restrict__ ln_g,     // [64]
    const float* __restrict__ ln_b,     // [64]
    float* __restrict__ etab)           // [64][64]
{
  __shared__ float h[64];
  __shared__ float A1[128];
  __shared__ float xs[64];
  const int r = blockIdx.x;
  const int t = threadIdx.x;

  if (t < 64) h[t] = embed[r * 64 + t];
  __syncthreads();

  {
    float acc = ff_b1[t];
    #pragma unroll 8
    for (int k = 0; k < 64; ++k)
      acc = fmaf(h[k], ff_w1[k * 128 + t], acc);
    A1[t] = fmaxf(acc, 0.f);
  }
  __syncthreads();

  if (t < 64) {
    float acc = ff_b2[t];
    #pragma unroll 8
    for (int k = 0; k < 128; ++k)
      acc = fmaf(A1[k], ff_w2[k * 64 + t], acc);
    xs[t] = acc + h[t];
  }
  __syncthreads();

  if (t < 64) {
    float s1 = 0.f;
    if (t < 4)
      for (int j = 0; j < 16; ++j) s1 += xs[t + 4 * j];
    s1 += __shfl_xor(s1, 1);
    s1 += __shfl_xor(s1, 2);
    s1 = __shfl(s1, 0);
    float mu = s1 * 0.015625f;

    float s2 = 0.f;
    if (t < 4)
      for (int j = 0; j < 16; ++j) {
        float d = xs[t + 4 * j] - mu;
        s2 = fmaf(d, d, s2);
      }
    s2 += __shfl_xor(s2, 1);
    s2 += __shfl_xor(s2, 2);
    s2 = __shfl(s2, 0);
    float var = s2 * 0.015625f;
    float rs  = rsqrtf(var + 1e-5f);

    etab[r * 64 + t] = fmaf((xs[t] - mu) * rs, ln_g[t], ln_b[t]);
  }
}

// ---------- Kernel 2: pair-layout 8-step Adam ----------
__device__ __forceinline__ void adam_upd(float& p, float& m, float& v,
                                         float g1, float g2, float cmsbr) {
  m = fmaf(0.9f, m, g1);
  v = fmaf(0.999f, v, g2);
  p = fmaf(-(m * cmsbr), __builtin_amdgcn_rsqf(fmaxf(v, 1e-30f)), p);
}

// Layout: lane = (h = lane>>5, u = lane&31); wave w owns inner dims 12w..12w+11,
// h-half owns 6 of them (off = 12w+6h). Lane holds the j = {2u, 2u+1} pair of
// w1 rows and c = {2u, 2u+1} pair of w2 columns for its 6 inner dims, so the
// 64-wide reductions become 1 in-register add + a 5-stage 32-lane butterfly.
__global__ __launch_bounds__(128, 3) void adapt_kernel(
    const int* __restrict__ seqs,       // [BATCH][32]
    const float* __restrict__ etab,     // [64][64]
    const float* __restrict__ mlp_w1,   // [64][24]
    const float* __restrict__ mlp_b1,   // [24]
    const float* __restrict__ mlp_w2,   // [24][64]
    const float* __restrict__ mlp_b2,   // [64]
    const float* __restrict__ out_w,    // [64][64]
    const float* __restrict__ out_b,    // [64]
    float* __restrict__ out)            // [BATCH][64]
{
  __shared__ float2 yb[2][2][2][32];   // [step parity][wave][h][u] -> y partial pair
  __shared__ __align__(16) float hqv[64];
  const int t    = threadIdx.x;        // 0..127
  const int lane = t & 63;
  const int w    = t >> 6;             // 0 or 1
  const int h    = lane >> 5;          // 0 or 1
  const int u    = lane & 31;          // 0..31
  const int s    = blockIdx.x;
  const int off  = 12 * w + 6 * h;     // first inner dim of this lane's 6

  int tok = (lane < NPOS) ? seqs[s * SEQN + 14 + lane] : 0;

  // state: lane owns w1[2u][off+m], w1[2u+1][off+m], w2[off+m][2u], w2[off+m][2u+1]
  float w1a[6], w1b[6], m1a[6], v1a[6], m1b[6], v1b[6];
  float w2a[6], w2b[6], m2a[6], v2a[6], m2b[6], v2b[6];
  #pragma unroll
  for (int m = 0; m < 6; ++m) {
    w1a[m] = mlp_w1[(2 * u)     * INNER + off + m];
    w1b[m] = mlp_w1[(2 * u + 1) * INNER + off + m];
    w2a[m] = mlp_w2[(off + m) * HID + 2 * u];
    w2b[m] = mlp_w2[(off + m) * HID + 2 * u + 1];
    m1a[m] = v1a[m] = m1b[m] = v1b[m] = 0.f;
    m2a[m] = v2a[m] = m2b[m] = v2b[m] = 0.f;
  }
  // b1: old-lane i_loop (= 6h+m) maps to u = 3h + m/2, slot parity m&1.
  // Owner lanes u in [3h, 3h+3) hold b1[off+2d], b1[off+2d+1], d = u-3h.
  const int  d    = u - 3 * h;
  const bool own1 = ((unsigned)d < 3u);
  float b1lo = own1 ? mlp_b1[off + 2 * d]     : 0.f;
  float b1hi = own1 ? mlp_b1[off + 2 * d + 1] : 0.f;
  float mb1l = 0.f, vb1l = 0.f, mb1h = 0.f, vb1h = 0.f;
  // b2: wave0 h0 lanes own b2[2u], b2[2u+1] (chain-start position, as old)
  const bool w0h0 = (w == 0) && (h == 0);
  float b2lo = w0h0 ? mlp_b2[2 * u]     : 0.f;
  float b2hi = w0h0 ? mlp_b2[2 * u + 1] : 0.f;
  float mb2l = 0.f, vb2l = 0.f, mb2h = 0.f, vb2h = 0.f;

  const bool o0 = (u == 3 * h);
  const bool o1 = (u == 3 * h + 1);
  const bool o2 = (u == 3 * h + 2);

  // first k,v rows, pair layout (dwordx2 from L2-resident etab)
  const float2* e2 = (const float2*)etab;
  int tk = __shfl(tok, 0), tv = __shfl(tok, 1);
  float2 kp = e2[tk * 32 + u];
  float2 vp = e2[tv * 32 + u];

  #pragma unroll 1
  for (int st = 0; st < 8; ++st) {
    const float cmsbr = CMSBR[st];

    // forward: z_i = allred(k_j * w1[j][i]) + b1, first stage in-register
    float p0[6], p1[6];
    #pragma unroll
    for (int m = 0; m < 6; ++m) { p0[m] = kp.x * w1a[m]; p1[m] = kp.y * w1b[m]; }
    p0[0] += o0 ? b1lo : 0.f;  p1[1] += o0 ? b1hi : 0.f;
    p0[2] += o1 ? b1lo : 0.f;  p1[3] += o1 ? b1hi : 0.f;
    p0[4] += o2 ? b1lo : 0.f;  p1[5] += o2 ? b1hi : 0.f;
    float a[6];
    #pragma unroll
    for (int m = 0; m < 6; ++m) a[m] = allred32(p0[m] + p1[m]);
    #pragma unroll
    for (int m = 0; m < 6; ++m) a[m] = fmaxf(a[m], 0.f);

    // y partials for c = 2u (x) and 2u+1 (y); b2 seeds the w0h0 chain
    float yp0 = w0h0 ? b2lo : 0.f;
    float yp1 = w0h0 ? b2hi : 0.f;
    #pragma unroll
    for (int m = 0; m < 6; ++m) {
      yp0 = fmaf(a[m], w2a[m], yp0);
      yp1 = fmaf(a[m], w2b[m], yp1);
    }
    yb[st & 1][w][h][u] = make_float2(yp0, yp1);
    __syncthreads();
    float2 q00 = yb[st & 1][0][0][u];
    float2 q01 = yb[st & 1][0][1][u];
    float2 q10 = yb[st & 1][1][0][u];
    float2 q11 = yb[st & 1][1][1][u];
    float y0  = (q00.x + q01.x) + (q10.x + q11.x);
    float y1  = (q00.y + q01.y) + (q10.y + q11.y);
    float dy0 = (y0 - vp.x) * 0.03125f;   // 2/64
    float dy1 = (y1 - vp.y) * 0.03125f;

    // prefetch next step's k,v (st=7 harmlessly loads q row twice)
    int pp1 = 2 * st + 2; pp1 = pp1 < 16 ? pp1 : 16;
    int pp2 = 2 * st + 3; pp2 = pp2 < 16 ? pp2 : 16;
    int tk2 = __shfl(tok, pp1), tv2 = __shfl(tok, pp2);
    float2 kn = e2[tk2 * 32 + u];
    float2 vn = e2[tv2 * 32 + u];

    // backward: dz_i = (z_i>0) * allred(w2[i][c]*dy_c), pair stage in-register
    float dz[6];
    #pragma unroll
    for (int m = 0; m < 6; ++m) {
      float b0 = w2a[m] * dy0;
      float b1 = w2b[m] * dy1;
      dz[m] = allred32(b0 + b1);
    }
    #pragma unroll
    for (int m = 0; m < 6; ++m) dz[m] = (a[m] > 0.f) ? dz[m] : 0.f;

    // Adam step st+1; gradient prefactors folded per step (exact old exprs)
    float k001  = 0.1f   * kp.x,        k101  = 0.1f   * kp.y;
    float k0s   = 0.001f * kp.x * kp.x, k1s   = 0.001f * kp.y * kp.y;
    float dy001 = 0.1f   * dy0,         dy101 = 0.1f   * dy1;
    float dy0s  = 0.001f * dy0 * dy0,   dy1s  = 0.001f * dy1 * dy1;
    #pragma unroll
    for (int m = 0; m < 6; ++m) {
      float dzs = dz[m] * dz[m];
      adam_upd(w1a[m], m1a[m], v1a[m], k001 * dz[m], k0s * dzs, cmsbr);
      adam_upd(w1b[m], m1b[m], v1b[m], k101 * dz[m], k1s * dzs, cmsbr);
      float as = a[m] * a[m];
      adam_upd(w2a[m], m2a[m], v2a[m], dy001 * a[m], dy0s * as, cmsbr);
      adam_upd(w2b[m], m2b[m], v2b[m], dy101 * a[m], dy1s * as, cmsbr);
    }
    // b1: owner lanes read their dz slots; non-owners compute garbage never read
    float glo = o0 ? dz[0] : (o1 ? dz[2] : dz[4]);
    float ghi = o0 ? dz[1] : (o1 ? dz[3] : dz[5]);
    adam_upd(b1lo, mb1l, vb1l, 0.1f * glo, 0.001f * (glo * glo), cmsbr);
    adam_upd(b1hi, mb1h, vb1h, 0.1f * ghi, 0.001f * (ghi * ghi), cmsbr);
    // b2: wave0 only (wave-uniform branch; wave1 keeps no b2 state)
    if (w == 0) {
      adam_upd(b2lo, mb2l, vb2l, dy001, dy0s, cmsbr);
      adam_upd(b2hi, mb2h, vb2h, dy101, dy1s, cmsbr);
    }

    kp = kn; vp = vn;
  }

  // final forward with q (kp holds q row after last prefetch)
  {
    float p0[6], p1[6];
    #pragma unroll
    for (int m = 0; m < 6; ++m) { p0[m] = kp.x * w1a[m]; p1[m] = kp.y * w1b[m]; }
    p0[0] += o0 ? b1lo : 0.f;  p1[1] += o0 ? b1hi : 0.f;
    p0[2] += o1 ? b1lo : 0.f;  p1[3] += o1 ? b1hi : 0.f;
    p0[4] += o2 ? b1lo : 0.f;  p1[5] += o2 ? b1hi : 0.f;
    float hp0 = w0h0 ? b2lo : 0.f;
    float hp1 = w0h0 ? b2hi : 0.f;
    #pragma unroll
    for (int m = 0; m < 6; ++m) {
      float aq = fmaxf(allred32(p0[m] + p1[m]), 0.f);
      hp0 = fmaf(aq, w2a[m], hp0);
      hp1 = fmaf(aq, w2b[m], hp1);
    }
    yb[0][w][h][u] = make_float2(hp0, hp1);
  }
  __syncthreads();
  if (t < 32) {   // wave0 h0: assemble hq pair and stage to LDS
    float2 f00 = yb[0][0][0][u], f01 = yb[0][0][1][u];
    float2 f10 = yb[0][1][0][u], f11 = yb[0][1][1][u];
    ((float2*)hqv)[u] = make_float2((f00.x + f01.x) + (f10.x + f11.x),
                                    (f00.y + f01.y) + (f10.y + f11.y));
  }
  __syncthreads();

  if (w == 0) {
    // out[s][c] = sum_j hq[j] * out_w[j][c] + out_b[c]   (lane = c)
    float acc = out_b[lane];
    const f32x4* hv = (const f32x4*)hqv;
    #pragma unroll
    for (int j4 = 0; j4 < 16; ++j4) {
      f32x4 h4 = hv[j4];
      acc = fmaf(h4.x, out_w[(4 * j4 + 0) * 64 + lane], acc);
      acc = fmaf(h4.y, out_w[(4 * j4 + 1) * 64 + lane], acc);
      acc = fmaf(h4.z, out_w[(4 * j4 + 2) * 64 + lane], acc);
      acc = fmaf(h4.w, out_w[(4 * j4 + 3) * 64 + lane], acc);
    }
    out[(size_t)s * 64 + lane] = acc;
  }
}

extern "C" void kernel_launch(void* const* d_in, const int* in_sizes, int n_in,
                              void* d_out, int out_size, void* d_ws, size_t ws_size,
                              hipStream_t stream) {
  const int*   seqs   = (const int*)d_in[0];
  const float* embed  = (const float*)d_in[1];
  const float* ff_w1  = (const float*)d_in[2];
  const float* ff_b1  = (const float*)d_in[3];
  const float* ff_w2  = (const float*)d_in[4];
  const float* ff_b2  = (const float*)d_in[5];
  const float* ln_g   = (const float*)d_in[6];
  const float* ln_b   = (const float*)d_in[7];
  const float* mlp_w1 = (const float*)d_in[8];
  const float* mlp_b1 = (const float*)d_in[9];
  const float* mlp_w2 = (const float*)d_in[10];
  const float* mlp_b2 = (const float*)d_in[11];
  const float* out_w  = (const float*)d_in[12];
  const float* out_b  = (const float*)d_in[13];

  float* etab = (float*)d_ws;   // 64*64 f32 = 16 KB

  build_table<<<64, 128, 0, stream>>>(
      embed, ff_w1, ff_b1, ff_w2, ff_b2, ln_g, ln_b, etab);
  adapt_kernel<<<BATCHN, 128, 0, stream>>>(
      seqs, etab, mlp_w1, mlp_b1, mlp_w2, mlp_b2, out_w, out_b,
      (float*)d_out);
}

// Round 2
// 179.571 us; speedup vs baseline: 1.1596x; 1.0159x over previous
//
#include <hip/hip_runtime.h>
#include <hip/hip_bf16.h>
#include <math.h>

// Problem constants
#define HID   64
#define VOCABN 64
#define INNER 24
#define SEQN  32
#define CAPN  8
#define NPOS  17
#define BATCHN 8192

typedef float f32x4 __attribute__((ext_vector_type(4)));
typedef float f32x2 __attribute__((ext_vector_type(2)));

// Packed-fp32 helpers: <2 x float> IR so LLVM can select v_pk_{fma,mul,add}_f32.
#if defined(__has_builtin)
#  if __has_builtin(__builtin_elementwise_fma)
#    define PK_FMA(a,b,c) __builtin_elementwise_fma((a),(b),(c))
#  endif
#  if __has_builtin(__builtin_elementwise_max)
#    define PK_MAX(a,b) __builtin_elementwise_max((a),(b))
#  endif
#endif
#ifndef PK_FMA
static __device__ __forceinline__ f32x2 pk_fma_fb(f32x2 a, f32x2 b, f32x2 c) {
  f32x2 r; r.x = fmaf(a.x, b.x, c.x); r.y = fmaf(a.y, b.y, c.y); return r;
}
#  define PK_FMA(a,b,c) pk_fma_fb((a),(b),(c))
#endif
#ifndef PK_MAX
static __device__ __forceinline__ f32x2 pk_max_fb(f32x2 a, f32x2 b) {
  f32x2 r; r.x = fmaxf(a.x, b.x); r.y = fmaxf(a.y, b.y); return r;
}
#  define PK_MAX(a,b) pk_max_fb((a),(b))
#endif

static __device__ __forceinline__ f32x2 sp2(float x) { return (f32x2){x, x}; }

// Per-step Adam prefactor (double-precision offline):
//   cmsbr[t] = LR * sqrt(1 - B2^(t+1)) / (1 - B1^(t+1)),  t = 0..7
static __device__ const float CMSBR[8] = {
  0.01581139f, 0.01176584f, 0.01010053f, 0.00918844f,
  0.00862495f, 0.00825540f, 0.00800653f, 0.00783856f
};

// ---------- 32-lane all-reduce over u = lane&31 (bit-exact lineage) ----------
__device__ __forceinline__ float allred32(float x) {
  int y;
  y = __builtin_amdgcn_update_dpp(__float_as_int(x), __float_as_int(x),
                                  0xB1, 0xF, 0xF, false);   // quad_perm u^1
  x += __int_as_float(y);
  y = __builtin_amdgcn_update_dpp(__float_as_int(x), __float_as_int(x),
                                  0x4E, 0xF, 0xF, false);   // quad_perm u^2
  x += __int_as_float(y);
  x += __int_as_float(__builtin_amdgcn_ds_swizzle(__float_as_int(x), 0x101F)); // u^4
  x += __int_as_float(__builtin_amdgcn_ds_swizzle(__float_as_int(x), 0x201F)); // u^8
  x += __int_as_float(__builtin_amdgcn_ds_swizzle(__float_as_int(x), 0x401F)); // u^16
  return x;
}

// ---------- Kernel 1: per-token encoder table (verbatim, passing) ----------
__global__ __launch_bounds__(128) void build_table(
    const float* __restrict__ embed,    // [64][64]
    const float* __restrict__ ff_w1,    // [64][128]
    const float* __restrict__ ff_b1,    // [128]
    const float* __restrict__ ff_w2,    // [128][64]
    const float* __restrict__ ff_b2,    // [64]
    const float* __restrict__ ln_g,     // [64]
    const float* __restrict__ ln_b,     // [64]
    float* __restrict__ etab)           // [64][64]
{
  __shared__ float h[64];
  __shared__ float A1[128];
  __shared__ float xs[64];
  const int r = blockIdx.x;
  const int t = threadIdx.x;

  if (t < 64) h[t] = embed[r * 64 + t];
  __syncthreads();

  {
    float acc = ff_b1[t];
    #pragma unroll 8
    for (int k = 0; k < 64; ++k)
      acc = fmaf(h[k], ff_w1[k * 128 + t], acc);
    A1[t] = fmaxf(acc, 0.f);
  }
  __syncthreads();

  if (t < 64) {
    float acc = ff_b2[t];
    #pragma unroll 8
    for (int k = 0; k < 128; ++k)
      acc = fmaf(A1[k], ff_w2[k * 64 + t], acc);
    xs[t] = acc + h[t];
  }
  __syncthreads();

  if (t < 64) {
    float s1 = 0.f;
    if (t < 4)
      for (int j = 0; j < 16; ++j) s1 += xs[t + 4 * j];
    s1 += __shfl_xor(s1, 1);
    s1 += __shfl_xor(s1, 2);
    s1 = __shfl(s1, 0);
    float mu = s1 * 0.015625f;

    float s2 = 0.f;
    if (t < 4)
      for (int j = 0; j < 16; ++j) {
        float d = xs[t + 4 * j] - mu;
        s2 = fmaf(d, d, s2);
      }
    s2 += __shfl_xor(s2, 1);
    s2 += __shfl_xor(s2, 2);
    s2 = __shfl(s2, 0);
    float var = s2 * 0.015625f;
    float rs  = rsqrtf(var + 1e-5f);

    etab[r * 64 + t] = fmaf((xs[t] - mu) * rs, ln_g[t], ln_b[t]);
  }
}

// ---------- Kernel 2: pair-layout 8-step Adam, packed-fp32 ----------
// Bit-exact per component with the scalar adam_upd of r9 lineage.
__device__ __forceinline__ void adam_pk(f32x2& p, f32x2& m, f32x2& v,
                                        f32x2 g1, f32x2 g2, float cmsbr) {
  m = PK_FMA(sp2(0.9f),   m, g1);
  v = PK_FMA(sp2(0.999f), v, g2);
  f32x2 vc = PK_MAX(v, sp2(1e-30f));
  f32x2 r; r.x = __builtin_amdgcn_rsqf(vc.x); r.y = __builtin_amdgcn_rsqf(vc.y);
  f32x2 t = m * sp2(cmsbr);
  p = PK_FMA(-t, r, p);
}

// Layout: lane = (h = lane>>5, u = lane&31); wave w owns inner dims 12w..12w+11,
// h-half owns 6 of them (off = 12w+6h). Lane holds the j = {2u, 2u+1} pair of
// w1 rows and c = {2u, 2u+1} pair of w2 columns for its 6 inner dims; all pair
// state is f32x2 so the independent a/b chains issue as packed VOP3P ops.
__global__ __launch_bounds__(128, 3) void adapt_kernel(
    const int* __restrict__ seqs,       // [BATCH][32]
    const float* __restrict__ etab,     // [64][64]
    const float* __restrict__ mlp_w1,   // [64][24]
    const float* __restrict__ mlp_b1,   // [24]
    const float* __restrict__ mlp_w2,   // [24][64]
    const float* __restrict__ mlp_b2,   // [64]
    const float* __restrict__ out_w,    // [64][64]
    const float* __restrict__ out_b,    // [64]
    float* __restrict__ out)            // [BATCH][64]
{
  __shared__ f32x2 yb[2][2][2][32];    // [step parity][wave][h][u] -> y partial pair
  __shared__ __align__(16) float hqv[64];
  const int t    = threadIdx.x;        // 0..127
  const int lane = t & 63;
  const int w    = t >> 6;             // 0 or 1
  const int h    = lane >> 5;          // 0 or 1
  const int u    = lane & 31;          // 0..31
  const int s    = blockIdx.x;
  const int off  = 12 * w + 6 * h;     // first inner dim of this lane's 6

  // Tokens are wave-uniform: read via uniform (scalar) loads, no bpermute.
  const int* __restrict__ srow = seqs + s * SEQN + 14;

  // state: lane owns w1[2u][off+m], w1[2u+1][off+m], w2[off+m][2u], w2[off+m][2u+1]
  f32x2 w1[6], m1[6], v1[6], w2[6], m2[6], v2[6];
  #pragma unroll
  for (int m = 0; m < 6; ++m) {
    f32x2 a; a.x = mlp_w1[(2 * u) * INNER + off + m];
             a.y = mlp_w1[(2 * u + 1) * INNER + off + m];
    w1[m] = a;
    w2[m] = *(const f32x2*)&mlp_w2[(off + m) * HID + 2 * u];
    m1[m] = sp2(0.f); v1[m] = sp2(0.f); m2[m] = sp2(0.f); v2[m] = sp2(0.f);
  }
  // b1: owner lanes u in [3h, 3h+3) hold b1[off+2d], b1[off+2d+1], d = u-3h.
  const int  d    = u - 3 * h;
  const bool own1 = ((unsigned)d < 3u);
  f32x2 b1v = own1 ? *(const f32x2*)&mlp_b1[off + 2 * d] : sp2(0.f);
  f32x2 mb1 = sp2(0.f), vb1 = sp2(0.f);
  // b2: wave0 h0 lanes own b2[2u], b2[2u+1]
  const bool w0h0 = (w == 0) && (h == 0);
  f32x2 b2v = w0h0 ? *(const f32x2*)&mlp_b2[2 * u] : sp2(0.f);
  f32x2 mb2 = sp2(0.f), vb2 = sp2(0.f);

  const bool o0 = (u == 3 * h);
  const bool o1 = (u == 3 * h + 1);
  const bool o2 = (u == 3 * h + 2);

  // first k,v rows, pair layout (dwordx2 from L2-resident etab)
  const f32x2* e2 = (const f32x2*)etab;
  f32x2 kp = e2[srow[0] * 32 + u];
  f32x2 vp = e2[srow[1] * 32 + u];

  #pragma unroll 1
  for (int st = 0; st < 8; ++st) {
    const float cmsbr = CMSBR[st];

    // forward: z_i = allred(k_j * w1[j][i]) + b1, pair stage in-register
    f32x2 pz[6];
    #pragma unroll
    for (int m = 0; m < 6; ++m) pz[m] = kp * w1[m];          // pk_mul
    pz[0].x += o0 ? b1v.x : 0.f;  pz[1].y += o0 ? b1v.y : 0.f;
    pz[2].x += o1 ? b1v.x : 0.f;  pz[3].y += o1 ? b1v.y : 0.f;
    pz[4].x += o2 ? b1v.x : 0.f;  pz[5].y += o2 ? b1v.y : 0.f;
    float a_[6];
    #pragma unroll
    for (int m = 0; m < 6; ++m) a_[m] = allred32(pz[m].x + pz[m].y);
    #pragma unroll
    for (int m = 0; m < 6; ++m) a_[m] = fmaxf(a_[m], 0.f);

    // y partials for c = {2u, 2u+1}; b2 seeds the w0h0 chain
    f32x2 yp = w0h0 ? b2v : sp2(0.f);
    #pragma unroll
    for (int m = 0; m < 6; ++m) yp = PK_FMA(sp2(a_[m]), w2[m], yp);  // pk_fma
    yb[st & 1][w][h][u] = yp;
    __syncthreads();
    f32x2 q00 = yb[st & 1][0][0][u];
    f32x2 q01 = yb[st & 1][0][1][u];
    f32x2 q10 = yb[st & 1][1][0][u];
    f32x2 q11 = yb[st & 1][1][1][u];
    f32x2 ys  = (q00 + q01) + (q10 + q11);                   // pk_add
    f32x2 dyv = (ys - vp) * sp2(0.03125f);                   // 2/64

    // prefetch next step's k,v (st=7 harmlessly loads q row twice)
    int pp1 = 2 * st + 2; pp1 = pp1 < 16 ? pp1 : 16;
    int pp2 = 2 * st + 3; pp2 = pp2 < 16 ? pp2 : 16;
    f32x2 kn = e2[srow[pp1] * 32 + u];
    f32x2 vn = e2[srow[pp2] * 32 + u];

    // backward: dz_i = (z_i>0) * allred(w2[i][c]*dy_c), pair stage in-register
    float dz[6];
    #pragma unroll
    for (int m = 0; m < 6; ++m) {
      f32x2 bb = w2[m] * dyv;                                // pk_mul
      dz[m] = allred32(bb.x + bb.y);
    }
    #pragma unroll
    for (int m = 0; m < 6; ++m) dz[m] = (a_[m] > 0.f) ? dz[m] : 0.f;

    // Adam step st+1; packed gradient prefactors (bit-exact commutations only)
    f32x2 k01  = kp * sp2(0.1f);            // (0.1*kx, 0.1*ky)
    f32x2 ksq  = (sp2(0.001f) * kp) * kp;   // ((0.001*kx)*kx, ...)
    f32x2 dy01 = dyv * sp2(0.1f);
    f32x2 dysq = (sp2(0.001f) * dyv) * dyv;
    #pragma unroll
    for (int m = 0; m < 6; ++m) {
      float dzs = dz[m] * dz[m];
      adam_pk(w1[m], m1[m], v1[m], k01 * sp2(dz[m]), ksq * sp2(dzs), cmsbr);
      float as = a_[m] * a_[m];
      adam_pk(w2[m], m2[m], v2[m], dy01 * sp2(a_[m]), dysq * sp2(as), cmsbr);
    }
    // b1: owner lanes read their dz slots; non-owners compute garbage never read
    float glo = o0 ? dz[0] : (o1 ? dz[2] : dz[4]);
    float ghi = o0 ? dz[1] : (o1 ? dz[3] : dz[5]);
    f32x2 g1b; g1b.x = 0.1f * glo;           g1b.y = 0.1f * ghi;
    f32x2 g2b; g2b.x = 0.001f * (glo * glo); g2b.y = 0.001f * (ghi * ghi);
    adam_pk(b1v, mb1, vb1, g1b, g2b, cmsbr);
    // b2: wave0 only (wave-uniform branch)
    if (w == 0) adam_pk(b2v, mb2, vb2, dy01, dysq, cmsbr);

    kp = kn; vp = vn;
  }

  // final forward with q (kp holds q row after last prefetch)
  {
    f32x2 pz[6];
    #pragma unroll
    for (int m = 0; m < 6; ++m) pz[m] = kp * w1[m];
    pz[0].x += o0 ? b1v.x : 0.f;  pz[1].y += o0 ? b1v.y : 0.f;
    pz[2].x += o1 ? b1v.x : 0.f;  pz[3].y += o1 ? b1v.y : 0.f;
    pz[4].x += o2 ? b1v.x : 0.f;  pz[5].y += o2 ? b1v.y : 0.f;
    f32x2 hpv = w0h0 ? b2v : sp2(0.f);
    #pragma unroll
    for (int m = 0; m < 6; ++m) {
      float aq = fmaxf(allred32(pz[m].x + pz[m].y), 0.f);
      hpv = PK_FMA(sp2(aq), w2[m], hpv);
    }
    yb[0][w][h][u] = hpv;
  }
  __syncthreads();
  if (t < 32) {   // wave0 h0: assemble hq pair and stage to LDS
    f32x2 f00 = yb[0][0][0][u], f01 = yb[0][0][1][u];
    f32x2 f10 = yb[0][1][0][u], f11 = yb[0][1][1][u];
    *(f32x2*)&hqv[2 * u] = (f00 + f01) + (f10 + f11);
  }
  __syncthreads();

  if (w == 0) {
    // out[s][c] = sum_j hq[j] * out_w[j][c] + out_b[c]   (lane = c)
    float acc = out_b[lane];
    const f32x4* hv = (const f32x4*)hqv;
    #pragma unroll
    for (int j4 = 0; j4 < 16; ++j4) {
      f32x4 h4 = hv[j4];
      acc = fmaf(h4.x, out_w[(4 * j4 + 0) * 64 + lane], acc);
      acc = fmaf(h4.y, out_w[(4 * j4 + 1) * 64 + lane], acc);
      acc = fmaf(h4.z, out_w[(4 * j4 + 2) * 64 + lane], acc);
      acc = fmaf(h4.w, out_w[(4 * j4 + 3) * 64 + lane], acc);
    }
    out[(size_t)s * 64 + lane] = acc;
  }
}

extern "C" void kernel_launch(void* const* d_in, const int* in_sizes, int n_in,
                              void* d_out, int out_size, void* d_ws, size_t ws_size,
                              hipStream_t stream) {
  const int*   seqs   = (const int*)d_in[0];
  const float* embed  = (const float*)d_in[1];
  const float* ff_w1  = (const float*)d_in[2];
  const float* ff_b1  = (const float*)d_in[3];
  const float* ff_w2  = (const float*)d_in[4];
  const float* ff_b2  = (const float*)d_in[5];
  const float* ln_g   = (const float*)d_in[6];
  const float* ln_b   = (const float*)d_in[7];
  const float* mlp_w1 = (const float*)d_in[8];
  const float* mlp_b1 = (const float*)d_in[9];
  const float* mlp_w2 = (const float*)d_in[10];
  const float* mlp_b2 = (const float*)d_in[11];
  const float* out_w  = (const float*)d_in[12];
  const float* out_b  = (const float*)d_in[13];

  float* etab = (float*)d_ws;   // 64*64 f32 = 16 KB

  build_table<<<64, 128, 0, stream>>>(
      embed, ff_w1, ff_b1, ff_w2, ff_b2, ln_g, ln_b, etab);
  adapt_kernel<<<BATCHN, 128, 0, stream>>>(
      seqs, etab, mlp_w1, mlp_b1, mlp_w2, mlp_b2, out_w, out_b,
      (float*)d_out);
}